// Round 10
// baseline (292.780 us; speedup 1.0000x reference)
//
#include <hip/hip_runtime.h>
#include <math.h>

// Problem constants
namespace {
constexpr int B_    = 2;
constexpr int C_    = 256;
constexpr int NHEAD = 4;
constexpr int HDIM  = 64;
constexpr int NTOK  = 4096;          // H*W
constexpr float SCALE = 0.125f;      // HDIM^-0.5
constexpr float LOG2E = 1.44269504f; // exp(x) = exp2(x*LOG2E)
constexpr int QKV_BLOCKS = B_ * (NTOK / 64);   // 128 (R9: q,k,v fused per block)
}

typedef _Float16 half8  __attribute__((ext_vector_type(8)));
typedef _Float16 half4  __attribute__((ext_vector_type(4)));
typedef __fp16   fp16x2 __attribute__((ext_vector_type(2)));  // pkrtz ret type
typedef float    floatx4 __attribute__((ext_vector_type(4)));
typedef int      int4v   __attribute__((ext_vector_type(4)));
typedef unsigned int uint2v __attribute__((ext_vector_type(2)));

// ---------------------------------------------------------------------------
// permlane swap helpers (R3-verified): builtins so the compiler models the
// cross-lane op and inserts VALU hazard NOPs.
// ---------------------------------------------------------------------------
__device__ __forceinline__ void plswap32(int &a, int &b) {
#if __has_builtin(__builtin_amdgcn_permlane32_swap)
    const uint2v r = __builtin_amdgcn_permlane32_swap((unsigned)a, (unsigned)b, false, false);
    a = (int)r[0]; b = (int)r[1];
#else
    asm volatile("s_nop 1\n\tv_permlane32_swap_b32 %0, %1\n\ts_nop 1"
                 : "+v"(a), "+v"(b));
#endif
}
__device__ __forceinline__ void plswap16(int &a, int &b) {
#if __has_builtin(__builtin_amdgcn_permlane16_swap)
    const uint2v r = __builtin_amdgcn_permlane16_swap((unsigned)a, (unsigned)b, false, false);
    a = (int)r[0]; b = (int)r[1];
#else
    asm volatile("s_nop 1\n\tv_permlane16_swap_b32 %0, %1\n\ts_nop 1"
                 : "+v"(a), "+v"(b));
#endif
}

// direct global->LDS DMA, 16 B per lane (R4-verified). lptr wave-uniform base.
__device__ __forceinline__ void gload_lds16(const _Float16* g, _Float16* l, int lane) {
#if __has_builtin(__builtin_amdgcn_global_load_lds)
    __builtin_amdgcn_global_load_lds(
        (const __attribute__((address_space(1))) void*)g,
        (__attribute__((address_space(3))) void*)l, 16, 0, 0);
#else
    *(half8*)((char*)l + lane * 16) = *(const half8*)g;  // fallback: reg staging
#endif
}

// fp32x8 -> half8 fragment load (inline W conversion)
__device__ __forceinline__ half8 ldcvt8(const float* p) {
    const float4 a = *(const float4*)p;
    const float4 b = *(const float4*)(p + 4);
    half8 h;
    h[0]=(_Float16)a.x; h[1]=(_Float16)a.y; h[2]=(_Float16)a.z; h[3]=(_Float16)a.w;
    h[4]=(_Float16)b.x; h[5]=(_Float16)b.y; h[6]=(_Float16)b.z; h[7]=(_Float16)b.w;
    return h;
}

// ---------------------------------------------------------------------------
// Kernel 1 (FUSED): blocks [0,128) = QKV projection with ALL THREE
// projections per block (R9: x^T staged ONCE instead of 3x -- deletes 2/3 of
// the x HBM reads and 2/3 of the scalar ds_write transpose cost); blocks
// [128, 4224) = pack_mask (R10-verified body). pack blocks keep the CUs fed
// while the fatter qkv blocks run (R7-verified concurrency mechanism).
// ---------------------------------------------------------------------------
__global__ __launch_bounds__(256) void qkv_pack(
    const float* __restrict__ x,
    const float* __restrict__ wq, const float* __restrict__ wk,
    const float* __restrict__ wv,
    const float* __restrict__ bq, const float* __restrict__ bk,
    const float* __restrict__ bv,
    const unsigned int* __restrict__ m32, unsigned int* __restrict__ packed,
    _Float16* __restrict__ qo, _Float16* __restrict__ ko,
    _Float16* __restrict__ vo)
{
    if (blockIdx.x >= QKV_BLOCKS) {
        // ================= pack_mask path =================
        int c0 = 0, c1 = 0, c2 = 0, c3 = 0;
        #pragma unroll
        for (int i = 0; i < 16; i++) {
            const unsigned int d = m32[i];
            c0 += (d == 0x00000001u);
            c1 += (d == 0x3F803F80u);
            c2 += (d == 0x3F800000u);
            c3 += (d == 0x01010101u);
        }
        int fmt = 1, best = c1;
        if (c0 > best) { best = c0; fmt = 0; }
        if (c2 > best) { best = c2; fmt = 2; }
        if (c3 > best) { best = c3; fmt = 3; }

        const unsigned int W = (blockIdx.x - QKV_BLOCKS) * 256 + threadIdx.x;
        unsigned int bits = 0;
        if (fmt == 1) {                       // bf16: 2 elems/dword, 16 dwords
            const uint4* p4 = (const uint4*)(m32 + (size_t)W * 16);
            #pragma unroll
            for (int i = 0; i < 4; i++) {
                const uint4 v = p4[i];
                const unsigned int d[4] = { v.x, v.y, v.z, v.w };
                #pragma unroll
                for (int j = 0; j < 4; j++) {
                    const int e = i * 8 + j * 2;
                    bits |= ((d[j] & 0xFFFFu) ? 1u : 0u) << e;
                    bits |= ((d[j] >> 16)     ? 1u : 0u) << (e + 1);
                }
            }
        } else if (fmt != 3) {                // int32 / fp32: 32 dwords
            const uint4* p4 = (const uint4*)(m32 + (size_t)W * 32);
            #pragma unroll
            for (int i = 0; i < 8; i++) {
                const uint4 v = p4[i];
                bits |= (v.x ? 1u : 0u) << (i * 4 + 0);
                bits |= (v.y ? 1u : 0u) << (i * 4 + 1);
                bits |= (v.z ? 1u : 0u) << (i * 4 + 2);
                bits |= (v.w ? 1u : 0u) << (i * 4 + 3);
            }
        } else {                              // uint8: 4 elems/dword, 8 dwords
            const uint4* p4 = (const uint4*)(m32 + (size_t)W * 8);
            #pragma unroll
            for (int i = 0; i < 2; i++) {
                const uint4 v = p4[i];
                const unsigned int d[4] = { v.x, v.y, v.z, v.w };
                #pragma unroll
                for (int j = 0; j < 4; j++) {
                    const int e = (i * 4 + j) * 4;
                    bits |= ((d[j] & 0x000000FFu) ? 1u : 0u) << (e + 0);
                    bits |= ((d[j] & 0x0000FF00u) ? 1u : 0u) << (e + 1);
                    bits |= ((d[j] & 0x00FF0000u) ? 1u : 0u) << (e + 2);
                    bits |= ((d[j] & 0xFF000000u) ? 1u : 0u) << (e + 3);
                }
            }
        }
        packed[W] = bits;
        return;
    }

    // ================= qkv path (all 3 projections) =================
    const int bid = blockIdx.x;          // 0..127
    const int b   = bid >> 6;            // 0..1
    const int nt  = bid & 63;

    const int t    = threadIdx.x;
    const int wid  = t >> 6;
    const int lane = t & 63;
    const int quad = lane >> 4;
    const int l15  = lane & 15;
    const int n0   = nt * 64;

    __shared__ _Float16 xsh[64 * 264];   // [tok][c] full C (resident)
    __shared__ _Float16 tbuf[64 * 72];   // epilogue transpose

    const int srow = t >> 2;             // 0..63
    const int sc   = (t & 3) * 16;       // 0,16,32,48

    // ---- stage x transposed ONCE: x[c][n] fp32 -> xsh[n][c] f16 (all 256 c)
    {
        const int cr = t >> 4;           // 0..15
        const int nu = (t & 15) * 4;     // token group
        const float* xb = x + (size_t)b * C_ * NTOK;
        #pragma unroll
        for (int cc = 0; cc < 16; cc++) {
            const int cl = cc * 16 + cr;             // 0..255
            const float4 v = *(const float4*)&xb[(size_t)cl * NTOK + n0 + nu];
            xsh[(nu + 0) * 264 + cl] = (_Float16)v.x;
            xsh[(nu + 1) * 264 + cl] = (_Float16)v.y;
            xsh[(nu + 2) * 264 + cl] = (_Float16)v.z;
            xsh[(nu + 3) * 264 + cl] = (_Float16)v.w;
        }
    }
    __syncthreads();   // xsh visible

    for (int p = 0; p < 3; p++) {
        const float* w    = (p == 0) ? wq : (p == 1) ? wk : wv;
        const float* bias = (p == 0) ? bq : (p == 1) ? bk : bv;
        const float* wrow = &w[(size_t)(wid * 16 + l15) * C_];   // + co0*C per h

        for (int h = 0; h < NHEAD; h++) {
            const int co0 = h * 64;
            floatx4 acc[4];
            #pragma unroll
            for (int i = 0; i < 4; i++) acc[i] = (floatx4)0.f;

            #pragma unroll
            for (int c0 = 0; c0 < C_; c0 += 64) {
                const half8 a0 = ldcvt8(&wrow[(size_t)co0 * C_ + c0 + quad * 8]);
                const half8 a1 = ldcvt8(&wrow[(size_t)co0 * C_ + c0 + 32 + quad * 8]);
                #pragma unroll
                for (int nt2 = 0; nt2 < 4; nt2++) {
                    const half8 b0 = *(const half8*)&xsh[(nt2 * 16 + l15) * 264 + c0 + quad * 8];
                    const half8 b1 = *(const half8*)&xsh[(nt2 * 16 + l15) * 264 + c0 + 32 + quad * 8];
                    acc[nt2] = __builtin_amdgcn_mfma_f32_16x16x32_f16(a0, b0, acc[nt2], 0, 0, 0);
                    acc[nt2] = __builtin_amdgcn_mfma_f32_16x16x32_f16(a1, b1, acc[nt2], 0, 0, 0);
                }
            }

            // bias (co = co0 + wid*16 + quad*4 + i)
            const float4 bb4 = *(const float4*)&bias[co0 + wid * 16 + quad * 4];
            const float bb[4] = { bb4.x, bb4.y, bb4.z, bb4.w };

            if (p < 2) {
                const float osc = (p == 0) ? (SCALE * LOG2E) : 1.0f;
                #pragma unroll
                for (int nt2 = 0; nt2 < 4; nt2++) {
                    half4 hv;
                    #pragma unroll
                    for (int i = 0; i < 4; i++)
                        hv[i] = (_Float16)((acc[nt2][i] + bb[i]) * osc);
                    *(half4*)&tbuf[(nt2 * 16 + l15) * 72 + wid * 16 + quad * 4] = hv;
                }
                __syncthreads();
                _Float16* dh = (p == 0 ? qo : ko) + (size_t)(b * NHEAD + h) * NTOK * HDIM;
                const half8 o0 = *(const half8*)&tbuf[srow * 72 + sc];
                const half8 o1 = *(const half8*)&tbuf[srow * 72 + sc + 8];
                *(half8*)&dh[(size_t)(n0 + srow) * HDIM + sc]     = o0;
                *(half8*)&dh[(size_t)(n0 + srow) * HDIM + sc + 8] = o1;
            } else {
                #pragma unroll
                for (int nt2 = 0; nt2 < 4; nt2++)
                    #pragma unroll
                    for (int i = 0; i < 4; i++)
                        tbuf[(wid * 16 + quad * 4 + i) * 72 + nt2 * 16 + l15] =
                            (_Float16)(acc[nt2][i] + bb[i]);
                __syncthreads();
                _Float16* vth = vo + (size_t)(b * NHEAD + h) * HDIM * NTOK;
                const half8 o0 = *(const half8*)&tbuf[srow * 72 + sc];
                const half8 o1 = *(const half8*)&tbuf[srow * 72 + sc + 8];
                *(half8*)&vth[(size_t)srow * NTOK + n0 + sc]     = o0;
                *(half8*)&vth[(size_t)srow * NTOK + n0 + sc + 8] = o1;
            }
            __syncthreads();   // tbuf reads done before next h/p rewrites it
        }
    }
}

// ---------------------------------------------------------------------------
// Kernel 2: MFMA attention, in-block K-split (REVERTED to R7-verified
// schedule after R8's counted-vmcnt pipeline regressed +7us: with 8 waves
// arriving staggered at the barrier, the DMA latency was already hidden and
// the triple-buffer machinery was pure overhead -- T-catalog regime gate).
// Dual q-tile per wave, swizzled global_load_lds staging, permlane P-handoff,
// 64 KB double-buffer, one __syncthreads per tile.
// ---------------------------------------------------------------------------
__global__ __launch_bounds__(512) void attn(
    const _Float16* __restrict__ q, const _Float16* __restrict__ k,
    const _Float16* __restrict__ vt, const unsigned int* __restrict__ mpacked,
    _Float16* __restrict__ ao)
{
    const int b  = blockIdx.z;
    const int h  = blockIdx.y;
    const int q0 = blockIdx.x * 128;
    const int t    = threadIdx.x;
    const int w    = t >> 6;             // 0..7
    const int lane = t & 63;
    const int quad = lane >> 4;
    const int l15  = lane & 15;
    const int half = w >> 2;             // key half
    const int w4   = w & 3;              // wave within half
    const int koff = half * (NTOK / 2);

    __shared__ __align__(16) char smem_raw[65536];
    _Float16* const sbase = (_Float16*)(smem_raw + half * 32768);
    // f16-unit offsets within a half: buf0 K=0 V=4096; buf1 K=8192 V=12288

    const size_t head_off = (size_t)(b * NHEAD + h) * NTOK * HDIM;
    const _Float16* qb  = q  + head_off;
    const _Float16* kb  = k  + head_off;
    const _Float16* vtb = vt + head_off;
    const unsigned int* mrow = mpacked + (size_t)b * NTOK * 128;

    const int qrowa = q0 + w4 * 16 + l15;
    const int qrowb = qrowa + 64;
    const half8 aq0a = *(const half8*)&qb[(size_t)qrowa * HDIM + quad * 8];
    const half8 aq1a = *(const half8*)&qb[(size_t)qrowa * HDIM + 32 + quad * 8];
    const half8 aq0b = *(const half8*)&qb[(size_t)qrowb * HDIM + quad * 8];
    const half8 aq1b = *(const half8*)&qb[(size_t)qrowb * HDIM + 32 + quad * 8];
    const unsigned int* mqa = &mrow[(size_t)qrowa * 128];
    const unsigned int* mqb = &mrow[(size_t)qrowb * 128];

    // fragment-read swizzle constants (chunk ^= row&7, 16B chunks = 8 f16)
    const int jr  = l15 & 7;
    const int xs0 = (quad ^ jr) << 3;          // k-elems 0..31 region
    const int xs1 = ((quad + 4) ^ jr) << 3;    // k-elems 32..63 region

    // mask words for tile 0 (refreshed one tile ahead in the loop)
    uint2 mwa = *(const uint2*)&mqa[koff >> 5];
    uint2 mwb = *(const uint2*)&mqb[koff >> 5];
    uint2 mwa_nxt = mwa, mwb_nxt = mwb;

    float l_a = 0.f, l_b = 0.f;
    floatx4 oacca[4], oaccb[4];
    #pragma unroll
    for (int i = 0; i < 4; i++) { oacca[i] = (floatx4)0.f; oaccb[i] = (floatx4)0.f; }

#define STAGE(WO, K0N)                                                        \
    {                                                                         \
        const int rl = lane >> 3;                    /* row within chunk */   \
        const int xc = ((lane & 7) ^ rl) << 3;       /* swizzled src chunk */ \
        const int c0 = w4 * 2, c1 = c0 + 1;                                   \
        gload_lds16(&kb[(size_t)((K0N) + c0 * 8 + rl) * HDIM + xc],           \
                    &sbase[(WO) + c0 * 512], lane);                           \
        gload_lds16(&kb[(size_t)((K0N) + c1 * 8 + rl) * HDIM + xc],           \
                    &sbase[(WO) + c1 * 512], lane);                           \
        gload_lds16(&vtb[(size_t)(c0 * 8 + rl) * NTOK + (K0N) + xc],          \
                    &sbase[(WO) + 4096 + c0 * 512], lane);                    \
        gload_lds16(&vtb[(size_t)(c1 * 8 + rl) * NTOK + (K0N) + xc],          \
                    &sbase[(WO) + 4096 + c1 * 512], lane);                    \
    }

    // ---- prologue: stage tile 0 into buf0 (barrier drains vmcnt)
    STAGE(0, koff)
    __syncthreads();

// masked exp2 for one ct-group of S-array SA; accumulates into LL
#define SOFTMAX_CT(SA, CT, WORD, SH, LL, Pa, Pb)                                  \
    {                                                                             \
        const unsigned nib = ((WORD) >> ((SH) + quad * 4)) & 0xFu;                \
        const float p0 = __builtin_amdgcn_exp2f((nib & 1u) ? SA[CT][0] : -3.0e38f);\
        const float p1 = __builtin_amdgcn_exp2f((nib & 2u) ? SA[CT][1] : -3.0e38f);\
        const float p2 = __builtin_amdgcn_exp2f((nib & 4u) ? SA[CT][2] : -3.0e38f);\
        const float p3 = __builtin_amdgcn_exp2f((nib & 8u) ? SA[CT][3] : -3.0e38f);\
        LL += (p0 + p1) + (p2 + p3);                                              \
        Pa = __builtin_bit_cast(int, __builtin_amdgcn_cvt_pkrtz(p0, p1));         \
        Pb = __builtin_bit_cast(int, __builtin_amdgcn_cvt_pkrtz(p2, p3));         \
    }

#define ATTN_TILE(RO, WO, KT, PF)                                                 \
    {                                                                             \
        if (PF) {                                                                 \
            const int k0n = koff + (KT) * 64 + 64;                                \
            STAGE(WO, k0n)                                                        \
            mwa_nxt = *(const uint2*)&mqa[k0n >> 5];                              \
            mwb_nxt = *(const uint2*)&mqb[k0n >> 5];                              \
        }                                                                         \
        floatx4 saa[4], sab[4];                                                   \
        __builtin_amdgcn_s_setprio(1);                                            \
        _Pragma("unroll")                                                         \
        for (int ct = 0; ct < 4; ct++) {                                          \
            saa[ct] = (floatx4)0.f; sab[ct] = (floatx4)0.f;                       \
            const half8 ka0 = *(const half8*)&sbase[(RO) + (ct*16 + l15)*64 + xs0];\
            const half8 ka1 = *(const half8*)&sbase[(RO) + (ct*16 + l15)*64 + xs1];\
            saa[ct] = __builtin_amdgcn_mfma_f32_16x16x32_f16(ka0, aq0a, saa[ct], 0, 0, 0); \
            saa[ct] = __builtin_amdgcn_mfma_f32_16x16x32_f16(ka1, aq1a, saa[ct], 0, 0, 0); \
            sab[ct] = __builtin_amdgcn_mfma_f32_16x16x32_f16(ka0, aq0b, sab[ct], 0, 0, 0); \
            sab[ct] = __builtin_amdgcn_mfma_f32_16x16x32_f16(ka1, aq1b, sab[ct], 0, 0, 0); \
        }                                                                         \
        __builtin_amdgcn_s_setprio(0);                                            \
        int A00,A01,A10,A11,A20,A21,A30,A31;                                      \
        int B00,B01,B10,B11,B20,B21,B30,B31;                                      \
        SOFTMAX_CT(saa, 0, mwa.x, 0,  l_a, A00, A01)                              \
        SOFTMAX_CT(saa, 1, mwa.x, 16, l_a, A10, A11)                              \
        SOFTMAX_CT(saa, 2, mwa.y, 0,  l_a, A20, A21)                              \
        SOFTMAX_CT(saa, 3, mwa.y, 16, l_a, A30, A31)                              \
        SOFTMAX_CT(sab, 0, mwb.x, 0,  l_b, B00, B01)                              \
        SOFTMAX_CT(sab, 1, mwb.x, 16, l_b, B10, B11)                              \
        SOFTMAX_CT(sab, 2, mwb.y, 0,  l_b, B20, B21)                              \
        SOFTMAX_CT(sab, 3, mwb.y, 16, l_b, B30, B31)                              \
        mwa = mwa_nxt; mwb = mwb_nxt;                                             \
        plswap32(A00, A10); plswap32(A01, A11);                                   \
        plswap32(A20, A30); plswap32(A21, A31);                                   \
        plswap16(A00, A10); plswap16(A01, A11);                                   \
        plswap16(A20, A30); plswap16(A21, A31);                                   \
        plswap32(B00, B10); plswap32(B01, B11);                                   \
        plswap32(B20, B30); plswap32(B21, B31);                                   \
        plswap16(B00, B10); plswap16(B01, B11);                                   \
        plswap16(B20, B30); plswap16(B21, B31);                                   \
        const half8 pb0a = __builtin_bit_cast(half8, (int4v){A00, A01, A10, A11});\
        const half8 pb1a = __builtin_bit_cast(half8, (int4v){A20, A21, A30, A31});\
        const half8 pb0b = __builtin_bit_cast(half8, (int4v){B00, B01, B10, B11});\
        const half8 pb1b = __builtin_bit_cast(half8, (int4v){B20, B21, B30, B31});\
        __builtin_amdgcn_s_setprio(1);                                            \
        _Pragma("unroll")                                                         \
        for (int dt = 0; dt < 4; dt++) {                                          \
            const half8 va0 = *(const half8*)&sbase[(RO) + 4096 + (dt*16 + l15)*64 + xs0];\
            const half8 va1 = *(const half8*)&sbase[(RO) + 4096 + (dt*16 + l15)*64 + xs1];\
            oacca[dt] = __builtin_amdgcn_mfma_f32_16x16x32_f16(va0, pb0a, oacca[dt], 0, 0, 0); \
            oacca[dt] = __builtin_amdgcn_mfma_f32_16x16x32_f16(va1, pb1a, oacca[dt], 0, 0, 0); \
            oaccb[dt] = __builtin_amdgcn_mfma_f32_16x16x32_f16(va0, pb0b, oaccb[dt], 0, 0, 0); \
            oaccb[dt] = __builtin_amdgcn_mfma_f32_16x16x32_f16(va1, pb1b, oaccb[dt], 0, 0, 0); \
        }                                                                         \
        __builtin_amdgcn_s_setprio(0);                                            \
        __syncthreads();                                                          \
    }

    for (int kt2 = 0; kt2 < 15; kt2++) {
        ATTN_TILE(0,    8192, 2 * kt2,     1)
        ATTN_TILE(8192, 0,    2 * kt2 + 1, 1)
    }
    ATTN_TILE(0,    8192, 30, 1)
    ATTN_TILE(8192, 0,    31, 0)

#undef ATTN_TILE
#undef SOFTMAX_CT
#undef STAGE

    // l: sum the 4 quad-partials for each qrow (lane bits 4,5)
    l_a += __shfl_xor(l_a, 16, 64);
    l_a += __shfl_xor(l_a, 32, 64);
    l_b += __shfl_xor(l_b, 16, 64);
    l_b += __shfl_xor(l_b, 32, 64);

    // ---- merge the two key-halves via explicit smem re-carve
    __syncthreads();
    float* oex = (float*)smem_raw;                 // 4 waves x 64 lanes x 32 f32 = 32 KB
    float* lex = (float*)(smem_raw + 32768);       // 128 floats
    if (w >= 4) {
        float* dst = &oex[((size_t)(w - 4) * 64 + lane) * 32];
        #pragma unroll
        for (int dt = 0; dt < 4; dt++) {
            *(floatx4*)&dst[dt * 4]      = oacca[dt];
            *(floatx4*)&dst[16 + dt * 4] = oaccb[dt];
        }
        if (quad == 0) {
            lex[(w - 4) * 16 + l15]      = l_a;
            lex[64 + (w - 4) * 16 + l15] = l_b;
        }
    }
    __syncthreads();
    if (w < 4) {
        const float* src = &oex[((size_t)w * 64 + lane) * 32];
        const float lta = l_a + lex[w * 16 + l15];
        const float ltb = l_b + lex[64 + w * 16 + l15];
        const float inva = (lta > 0.f) ? (1.0f / lta) : 0.f;
        const float invb = (ltb > 0.f) ? (1.0f / ltb) : 0.f;
        _Float16* aoba = ao + ((size_t)b * NTOK + q0 + w * 16 + l15) * C_ + h * 64;
        _Float16* aobb = ao + ((size_t)b * NTOK + q0 + 64 + w * 16 + l15) * C_ + h * 64;
        #pragma unroll
        for (int dt = 0; dt < 4; dt++) {
            const floatx4 o2a = *(const floatx4*)&src[dt * 4];
            const floatx4 o2b = *(const floatx4*)&src[16 + dt * 4];
            half4 ra, rb;
            #pragma unroll
            for (int rr = 0; rr < 4; rr++) {
                ra[rr] = (_Float16)((oacca[dt][rr] + o2a[rr]) * inva);
                rb[rr] = (_Float16)((oaccb[dt][rr] + o2b[rr]) * invb);
            }
            *(half4*)&aoba[dt * 16 + quad * 4] = ra;
            *(half4*)&aobb[dt * 16 + quad * 4] = rb;
        }
    }
}

// ---------------------------------------------------------------------------
// Kernel 3: output projection via MFMA (R7-verified: direct-global operands,
// inline W conversion, no main-loop LDS/barriers). UNCHANGED.
// ---------------------------------------------------------------------------
__global__ __launch_bounds__(256) void out_mfma(
    const _Float16* __restrict__ ao, const float* __restrict__ wo,
    const float* __restrict__ bo, float* __restrict__ out)
{
    const int nt  = blockIdx.x;
    const int cot = blockIdx.y;
    const int b   = blockIdx.z;
    const int t    = threadIdx.x;
    const int wid  = t >> 6;
    const int lane = t & 63;
    const int quad = lane >> 4;
    const int l15  = lane & 15;
    const int n0  = nt * 64;
    const int co0 = cot * 64;

    __shared__ float tf[64 * 68];        // [co][tok] epilogue

    floatx4 acc[4];
    #pragma unroll
    for (int i = 0; i < 4; i++) acc[i] = (floatx4)0.f;

    const float* wrow = &wo[(size_t)(co0 + wid * 16 + l15) * C_];
    const _Float16* aob  = ao + ((size_t)b * NTOK + n0) * C_;

    #pragma unroll
    for (int c0 = 0; c0 < C_; c0 += 64) {
        const half8 a0 = ldcvt8(&wrow[c0 + quad * 8]);
        const half8 a1 = ldcvt8(&wrow[c0 + 32 + quad * 8]);
        #pragma unroll
        for (int nt2 = 0; nt2 < 4; nt2++) {
            const half8 b0 = *(const half8*)&aob[(size_t)(nt2 * 16 + l15) * C_ + c0 + quad * 8];
            const half8 b1 = *(const half8*)&aob[(size_t)(nt2 * 16 + l15) * C_ + c0 + 32 + quad * 8];
            acc[nt2] = __builtin_amdgcn_mfma_f32_16x16x32_f16(a0, b0, acc[nt2], 0, 0, 0);
            acc[nt2] = __builtin_amdgcn_mfma_f32_16x16x32_f16(a1, b1, acc[nt2], 0, 0, 0);
        }
    }

    // epilogue: D[co][tok] -> tf, then coalesced fp32 rows + bias
    #pragma unroll
    for (int nt2 = 0; nt2 < 4; nt2++)
        #pragma unroll
        for (int i = 0; i < 4; i++)
            tf[(wid * 16 + quad * 4 + i) * 68 + nt2 * 16 + l15] = acc[nt2][i];
    __syncthreads();

    const int row = t >> 2;              // co local
    const int c4  = (t & 3) * 16;        // tok local
    const float bb = bo[co0 + row];
    float* orow = &out[((size_t)(b * C_ + co0 + row)) * NTOK + n0 + c4];
    #pragma unroll
    for (int u = 0; u < 4; u++) {
        float4 v = *(const float4*)&tf[row * 68 + c4 + u * 4];
        v.x += bb; v.y += bb; v.z += bb; v.w += bb;
        *(float4*)&orow[u * 4] = v;
    }
}

// ---------------------------------------------------------------------------
extern "C" void kernel_launch(void* const* d_in, const int* in_sizes, int n_in,
                              void* d_out, int out_size, void* d_ws, size_t ws_size,
                              hipStream_t stream) {
    const float* x    = (const float*)d_in[0];          // fp32
    const void*  mask = d_in[1];                        // dtype auto-detected
    const float* wq   = (const float*)d_in[2];
    const float* bq   = (const float*)d_in[3];
    const float* wk   = (const float*)d_in[4];
    const float* bk   = (const float*)d_in[5];
    const float* wv   = (const float*)d_in[6];
    const float* bv   = (const float*)d_in[7];
    const float* wo   = (const float*)d_in[8];
    const float* bo   = (const float*)d_in[9];
    float* out = (float*)d_out;                         // fp32

    // workspace layout (f16 units):
    //   q,k,vt,ao: 4 x 2,097,152   | mpacked: 1,048,576 u32 (= 2,097,152)
    const size_t qkv_elems = (size_t)B_ * NHEAD * NTOK * HDIM;  // == B*NTOK*C_
    _Float16* wsh = (_Float16*)d_ws;
    _Float16* qbuf  = wsh;
    _Float16* kbuf  = wsh + qkv_elems;
    _Float16* vtbuf = wsh + 2 * qkv_elems;
    _Float16* aobuf = wsh + 3 * qkv_elems;
    unsigned int* mpacked = (unsigned int*)(wsh + 4 * qkv_elems);

    qkv_pack<<<dim3(QKV_BLOCKS + (B_ * NTOK * 128) / 256), 256, 0, stream>>>(
        x, wq, wk, wv, bq, bk, bv,
        (const unsigned int*)mask, mpacked, qbuf, kbuf, vtbuf);
    attn<<<dim3(NTOK / 128, NHEAD, B_), 512, 0, stream>>>(
        qbuf, kbuf, vtbuf, mpacked, aobuf);
    out_mfma<<<dim3(NTOK / 64, C_ / 64, B_), 256, 0, stream>>>(
        aobuf, wo, bo, out);
}

// Round 11
// 284.633 us; speedup vs baseline: 1.0286x; 1.0286x over previous
//
#include <hip/hip_runtime.h>
#include <math.h>

// Problem constants
namespace {
constexpr int B_    = 2;
constexpr int C_    = 256;
constexpr int NHEAD = 4;
constexpr int HDIM  = 64;
constexpr int NTOK  = 4096;          // H*W
constexpr float SCALE = 0.125f;      // HDIM^-0.5
constexpr float LOG2E = 1.44269504f; // exp(x) = exp2(x*LOG2E)
constexpr int QKV_BLOCKS = 3 * B_ * (NTOK / 64);   // 384 (R7: one projection per block)
}

typedef _Float16 half8  __attribute__((ext_vector_type(8)));
typedef _Float16 half4  __attribute__((ext_vector_type(4)));
typedef __fp16   fp16x2 __attribute__((ext_vector_type(2)));  // pkrtz ret type
typedef float    floatx4 __attribute__((ext_vector_type(4)));
typedef int      int4v   __attribute__((ext_vector_type(4)));
typedef unsigned int uint2v __attribute__((ext_vector_type(2)));

// ---------------------------------------------------------------------------
// permlane swap helpers (R3-verified): builtins so the compiler models the
// cross-lane op and inserts VALU hazard NOPs.
// ---------------------------------------------------------------------------
__device__ __forceinline__ void plswap32(int &a, int &b) {
#if __has_builtin(__builtin_amdgcn_permlane32_swap)
    const uint2v r = __builtin_amdgcn_permlane32_swap((unsigned)a, (unsigned)b, false, false);
    a = (int)r[0]; b = (int)r[1];
#else
    asm volatile("s_nop 1\n\tv_permlane32_swap_b32 %0, %1\n\ts_nop 1"
                 : "+v"(a), "+v"(b));
#endif
}
__device__ __forceinline__ void plswap16(int &a, int &b) {
#if __has_builtin(__builtin_amdgcn_permlane16_swap)
    const uint2v r = __builtin_amdgcn_permlane16_swap((unsigned)a, (unsigned)b, false, false);
    a = (int)r[0]; b = (int)r[1];
#else
    asm volatile("s_nop 1\n\tv_permlane16_swap_b32 %0, %1\n\ts_nop 1"
                 : "+v"(a), "+v"(b));
#endif
}

// direct global->LDS DMA, 16 B per lane (R4-verified). lptr wave-uniform base.
__device__ __forceinline__ void gload_lds16(const _Float16* g, _Float16* l, int lane) {
#if __has_builtin(__builtin_amdgcn_global_load_lds)
    __builtin_amdgcn_global_load_lds(
        (const __attribute__((address_space(1))) void*)g,
        (__attribute__((address_space(3))) void*)l, 16, 0, 0);
#else
    *(half8*)((char*)l + lane * 16) = *(const half8*)g;  // fallback: reg staging
#endif
}

// fp32x8 -> half8 fragment load (inline W conversion)
__device__ __forceinline__ half8 ldcvt8(const float* p) {
    const float4 a = *(const float4*)p;
    const float4 b = *(const float4*)(p + 4);
    half8 h;
    h[0]=(_Float16)a.x; h[1]=(_Float16)a.y; h[2]=(_Float16)a.z; h[3]=(_Float16)a.w;
    h[4]=(_Float16)b.x; h[5]=(_Float16)b.y; h[6]=(_Float16)b.z; h[7]=(_Float16)b.w;
    return h;
}

// ---------------------------------------------------------------------------
// Kernel 1 (FUSED, R7-verified best): blocks [0,384) = QKV projection, ONE
// projection per block (R9's 3-proj merge regressed +9us: 128 fat blocks
// left half the CUs without qkv work -- traffic saving << parallelism loss);
// blocks [384, 4480) = pack_mask. pack is HBM-BW-bound, qkv is MFMA-bound;
// the fused launch lets them co-run on different pipes.
// ---------------------------------------------------------------------------
__global__ __launch_bounds__(256) void qkv_pack(
    const float* __restrict__ x,
    const float* __restrict__ wq, const float* __restrict__ wk,
    const float* __restrict__ wv,
    const float* __restrict__ bq, const float* __restrict__ bk,
    const float* __restrict__ bv,
    const unsigned int* __restrict__ m32, unsigned int* __restrict__ packed,
    _Float16* __restrict__ qo, _Float16* __restrict__ ko,
    _Float16* __restrict__ vo)
{
    if (blockIdx.x >= QKV_BLOCKS) {
        // ================= pack_mask path =================
        int c0 = 0, c1 = 0, c2 = 0, c3 = 0;
        #pragma unroll
        for (int i = 0; i < 16; i++) {
            const unsigned int d = m32[i];
            c0 += (d == 0x00000001u);
            c1 += (d == 0x3F803F80u);
            c2 += (d == 0x3F800000u);
            c3 += (d == 0x01010101u);
        }
        int fmt = 1, best = c1;
        if (c0 > best) { best = c0; fmt = 0; }
        if (c2 > best) { best = c2; fmt = 2; }
        if (c3 > best) { best = c3; fmt = 3; }

        const unsigned int W = (blockIdx.x - QKV_BLOCKS) * 256 + threadIdx.x;
        unsigned int bits = 0;
        if (fmt == 1) {                       // bf16: 2 elems/dword, 16 dwords
            const uint4* p4 = (const uint4*)(m32 + (size_t)W * 16);
            #pragma unroll
            for (int i = 0; i < 4; i++) {
                const uint4 v = p4[i];
                const unsigned int d[4] = { v.x, v.y, v.z, v.w };
                #pragma unroll
                for (int j = 0; j < 4; j++) {
                    const int e = i * 8 + j * 2;
                    bits |= ((d[j] & 0xFFFFu) ? 1u : 0u) << e;
                    bits |= ((d[j] >> 16)     ? 1u : 0u) << (e + 1);
                }
            }
        } else if (fmt != 3) {                // int32 / fp32: 32 dwords
            const uint4* p4 = (const uint4*)(m32 + (size_t)W * 32);
            #pragma unroll
            for (int i = 0; i < 8; i++) {
                const uint4 v = p4[i];
                bits |= (v.x ? 1u : 0u) << (i * 4 + 0);
                bits |= (v.y ? 1u : 0u) << (i * 4 + 1);
                bits |= (v.z ? 1u : 0u) << (i * 4 + 2);
                bits |= (v.w ? 1u : 0u) << (i * 4 + 3);
            }
        } else {                              // uint8: 4 elems/dword, 8 dwords
            const uint4* p4 = (const uint4*)(m32 + (size_t)W * 8);
            #pragma unroll
            for (int i = 0; i < 2; i++) {
                const uint4 v = p4[i];
                const unsigned int d[4] = { v.x, v.y, v.z, v.w };
                #pragma unroll
                for (int j = 0; j < 4; j++) {
                    const int e = (i * 4 + j) * 4;
                    bits |= ((d[j] & 0x000000FFu) ? 1u : 0u) << (e + 0);
                    bits |= ((d[j] & 0x0000FF00u) ? 1u : 0u) << (e + 1);
                    bits |= ((d[j] & 0x00FF0000u) ? 1u : 0u) << (e + 2);
                    bits |= ((d[j] & 0xFF000000u) ? 1u : 0u) << (e + 3);
                }
            }
        }
        packed[W] = bits;
        return;
    }

    // ================= qkv path =================
    const int bid = blockIdx.x;
    const int p   = bid >> 7;            // 0..2
    const int b   = (bid >> 6) & 1;
    const int nt  = bid & 63;

    const float* w    = (p == 0) ? wq : (p == 1) ? wk : wv;
    const float* bias = (p == 0) ? bq : (p == 1) ? bk : bv;

    const int t    = threadIdx.x;
    const int wid  = t >> 6;
    const int lane = t & 63;
    const int quad = lane >> 4;
    const int l15  = lane & 15;
    const int n0   = nt * 64;

    __shared__ _Float16 xsh[64 * 264];   // [tok][c] full C (resident)
    __shared__ _Float16 tbuf[64 * 72];   // epilogue transpose

    const int srow = t >> 2;             // 0..63
    const int sc   = (t & 3) * 16;       // 0,16,32,48

    // ---- stage x transposed ONCE: x[c][n] fp32 -> xsh[n][c] f16 (all 256 c)
    {
        const int cr = t >> 4;           // 0..15
        const int nu = (t & 15) * 4;     // token group
        const float* xb = x + (size_t)b * C_ * NTOK;
        #pragma unroll
        for (int cc = 0; cc < 16; cc++) {
            const int cl = cc * 16 + cr;             // 0..255
            const float4 v = *(const float4*)&xb[(size_t)cl * NTOK + n0 + nu];
            xsh[(nu + 0) * 264 + cl] = (_Float16)v.x;
            xsh[(nu + 1) * 264 + cl] = (_Float16)v.y;
            xsh[(nu + 2) * 264 + cl] = (_Float16)v.z;
            xsh[(nu + 3) * 264 + cl] = (_Float16)v.w;
        }
    }
    __syncthreads();   // xsh visible

    const float* wrow = &w[(size_t)(wid * 16 + l15) * C_];   // + co0*C per h

    for (int h = 0; h < NHEAD; h++) {
        const int co0 = h * 64;
        floatx4 acc[4];
        #pragma unroll
        for (int i = 0; i < 4; i++) acc[i] = (floatx4)0.f;

        #pragma unroll
        for (int c0 = 0; c0 < C_; c0 += 64) {
            const half8 a0 = ldcvt8(&wrow[(size_t)co0 * C_ + c0 + quad * 8]);
            const half8 a1 = ldcvt8(&wrow[(size_t)co0 * C_ + c0 + 32 + quad * 8]);
            #pragma unroll
            for (int nt2 = 0; nt2 < 4; nt2++) {
                const half8 b0 = *(const half8*)&xsh[(nt2 * 16 + l15) * 264 + c0 + quad * 8];
                const half8 b1 = *(const half8*)&xsh[(nt2 * 16 + l15) * 264 + c0 + 32 + quad * 8];
                acc[nt2] = __builtin_amdgcn_mfma_f32_16x16x32_f16(a0, b0, acc[nt2], 0, 0, 0);
                acc[nt2] = __builtin_amdgcn_mfma_f32_16x16x32_f16(a1, b1, acc[nt2], 0, 0, 0);
            }
        }

        // bias (co = co0 + wid*16 + quad*4 + i)
        const float4 bb4 = *(const float4*)&bias[co0 + wid * 16 + quad * 4];
        const float bb[4] = { bb4.x, bb4.y, bb4.z, bb4.w };

        if (p < 2) {
            const float osc = (p == 0) ? (SCALE * LOG2E) : 1.0f;
            #pragma unroll
            for (int nt2 = 0; nt2 < 4; nt2++) {
                half4 hv;
                #pragma unroll
                for (int i = 0; i < 4; i++)
                    hv[i] = (_Float16)((acc[nt2][i] + bb[i]) * osc);
                *(half4*)&tbuf[(nt2 * 16 + l15) * 72 + wid * 16 + quad * 4] = hv;
            }
            __syncthreads();
            _Float16* dh = (p == 0 ? qo : ko) + (size_t)(b * NHEAD + h) * NTOK * HDIM;
            const half8 o0 = *(const half8*)&tbuf[srow * 72 + sc];
            const half8 o1 = *(const half8*)&tbuf[srow * 72 + sc + 8];
            *(half8*)&dh[(size_t)(n0 + srow) * HDIM + sc]     = o0;
            *(half8*)&dh[(size_t)(n0 + srow) * HDIM + sc + 8] = o1;
        } else {
            #pragma unroll
            for (int nt2 = 0; nt2 < 4; nt2++)
                #pragma unroll
                for (int i = 0; i < 4; i++)
                    tbuf[(wid * 16 + quad * 4 + i) * 72 + nt2 * 16 + l15] =
                        (_Float16)(acc[nt2][i] + bb[i]);
            __syncthreads();
            _Float16* vth = vo + (size_t)(b * NHEAD + h) * HDIM * NTOK;
            const half8 o0 = *(const half8*)&tbuf[srow * 72 + sc];
            const half8 o1 = *(const half8*)&tbuf[srow * 72 + sc + 8];
            *(half8*)&vth[(size_t)srow * NTOK + n0 + sc]     = o0;
            *(half8*)&vth[(size_t)srow * NTOK + n0 + sc + 8] = o1;
        }
        __syncthreads();   // tbuf reads done before next h rewrites it
    }
}

// ---------------------------------------------------------------------------
// Kernel 2: MFMA attention, in-block K-split (R7-verified best). Dual q-tile
// per wave, swizzled global_load_lds staging, permlane P-handoff, 64 KB
// double-buffer, one __syncthreads per tile. (R8's counted-vmcnt pipeline
// regressed +7us -- regime gate; reverted.)
// ---------------------------------------------------------------------------
__global__ __launch_bounds__(512) void attn(
    const _Float16* __restrict__ q, const _Float16* __restrict__ k,
    const _Float16* __restrict__ vt, const unsigned int* __restrict__ mpacked,
    _Float16* __restrict__ ao)
{
    const int b  = blockIdx.z;
    const int h  = blockIdx.y;
    const int q0 = blockIdx.x * 128;
    const int t    = threadIdx.x;
    const int w    = t >> 6;             // 0..7
    const int lane = t & 63;
    const int quad = lane >> 4;
    const int l15  = lane & 15;
    const int half = w >> 2;             // key half
    const int w4   = w & 3;              // wave within half
    const int koff = half * (NTOK / 2);

    __shared__ __align__(16) char smem_raw[65536];
    _Float16* const sbase = (_Float16*)(smem_raw + half * 32768);
    // f16-unit offsets within a half: buf0 K=0 V=4096; buf1 K=8192 V=12288

    const size_t head_off = (size_t)(b * NHEAD + h) * NTOK * HDIM;
    const _Float16* qb  = q  + head_off;
    const _Float16* kb  = k  + head_off;
    const _Float16* vtb = vt + head_off;
    const unsigned int* mrow = mpacked + (size_t)b * NTOK * 128;

    const int qrowa = q0 + w4 * 16 + l15;
    const int qrowb = qrowa + 64;
    const half8 aq0a = *(const half8*)&qb[(size_t)qrowa * HDIM + quad * 8];
    const half8 aq1a = *(const half8*)&qb[(size_t)qrowa * HDIM + 32 + quad * 8];
    const half8 aq0b = *(const half8*)&qb[(size_t)qrowb * HDIM + quad * 8];
    const half8 aq1b = *(const half8*)&qb[(size_t)qrowb * HDIM + 32 + quad * 8];
    const unsigned int* mqa = &mrow[(size_t)qrowa * 128];
    const unsigned int* mqb = &mrow[(size_t)qrowb * 128];

    // fragment-read swizzle constants (chunk ^= row&7, 16B chunks = 8 f16)
    const int jr  = l15 & 7;
    const int xs0 = (quad ^ jr) << 3;          // k-elems 0..31 region
    const int xs1 = ((quad + 4) ^ jr) << 3;    // k-elems 32..63 region

    // mask words for tile 0 (refreshed one tile ahead in the loop)
    uint2 mwa = *(const uint2*)&mqa[koff >> 5];
    uint2 mwb = *(const uint2*)&mqb[koff >> 5];
    uint2 mwa_nxt = mwa, mwb_nxt = mwb;

    float l_a = 0.f, l_b = 0.f;
    floatx4 oacca[4], oaccb[4];
    #pragma unroll
    for (int i = 0; i < 4; i++) { oacca[i] = (floatx4)0.f; oaccb[i] = (floatx4)0.f; }

#define STAGE(WO, K0N)                                                        \
    {                                                                         \
        const int rl = lane >> 3;                    /* row within chunk */   \
        const int xc = ((lane & 7) ^ rl) << 3;       /* swizzled src chunk */ \
        const int c0 = w4 * 2, c1 = c0 + 1;                                   \
        gload_lds16(&kb[(size_t)((K0N) + c0 * 8 + rl) * HDIM + xc],           \
                    &sbase[(WO) + c0 * 512], lane);                           \
        gload_lds16(&kb[(size_t)((K0N) + c1 * 8 + rl) * HDIM + xc],           \
                    &sbase[(WO) + c1 * 512], lane);                           \
        gload_lds16(&vtb[(size_t)(c0 * 8 + rl) * NTOK + (K0N) + xc],          \
                    &sbase[(WO) + 4096 + c0 * 512], lane);                    \
        gload_lds16(&vtb[(size_t)(c1 * 8 + rl) * NTOK + (K0N) + xc],          \
                    &sbase[(WO) + 4096 + c1 * 512], lane);                    \
    }

    // ---- prologue: stage tile 0 into buf0 (barrier drains vmcnt)
    STAGE(0, koff)
    __syncthreads();

// masked exp2 for one ct-group of S-array SA; accumulates into LL
#define SOFTMAX_CT(SA, CT, WORD, SH, LL, Pa, Pb)                                  \
    {                                                                             \
        const unsigned nib = ((WORD) >> ((SH) + quad * 4)) & 0xFu;                \
        const float p0 = __builtin_amdgcn_exp2f((nib & 1u) ? SA[CT][0] : -3.0e38f);\
        const float p1 = __builtin_amdgcn_exp2f((nib & 2u) ? SA[CT][1] : -3.0e38f);\
        const float p2 = __builtin_amdgcn_exp2f((nib & 4u) ? SA[CT][2] : -3.0e38f);\
        const float p3 = __builtin_amdgcn_exp2f((nib & 8u) ? SA[CT][3] : -3.0e38f);\
        LL += (p0 + p1) + (p2 + p3);                                              \
        Pa = __builtin_bit_cast(int, __builtin_amdgcn_cvt_pkrtz(p0, p1));         \
        Pb = __builtin_bit_cast(int, __builtin_amdgcn_cvt_pkrtz(p2, p3));         \
    }

#define ATTN_TILE(RO, WO, KT, PF)                                                 \
    {                                                                             \
        if (PF) {                                                                 \
            const int k0n = koff + (KT) * 64 + 64;                                \
            STAGE(WO, k0n)                                                        \
            mwa_nxt = *(const uint2*)&mqa[k0n >> 5];                              \
            mwb_nxt = *(const uint2*)&mqb[k0n >> 5];                              \
        }                                                                         \
        floatx4 saa[4], sab[4];                                                   \
        __builtin_amdgcn_s_setprio(1);                                            \
        _Pragma("unroll")                                                         \
        for (int ct = 0; ct < 4; ct++) {                                          \
            saa[ct] = (floatx4)0.f; sab[ct] = (floatx4)0.f;                       \
            const half8 ka0 = *(const half8*)&sbase[(RO) + (ct*16 + l15)*64 + xs0];\
            const half8 ka1 = *(const half8*)&sbase[(RO) + (ct*16 + l15)*64 + xs1];\
            saa[ct] = __builtin_amdgcn_mfma_f32_16x16x32_f16(ka0, aq0a, saa[ct], 0, 0, 0); \
            saa[ct] = __builtin_amdgcn_mfma_f32_16x16x32_f16(ka1, aq1a, saa[ct], 0, 0, 0); \
            sab[ct] = __builtin_amdgcn_mfma_f32_16x16x32_f16(ka0, aq0b, sab[ct], 0, 0, 0); \
            sab[ct] = __builtin_amdgcn_mfma_f32_16x16x32_f16(ka1, aq1b, sab[ct], 0, 0, 0); \
        }                                                                         \
        __builtin_amdgcn_s_setprio(0);                                            \
        int A00,A01,A10,A11,A20,A21,A30,A31;                                      \
        int B00,B01,B10,B11,B20,B21,B30,B31;                                      \
        SOFTMAX_CT(saa, 0, mwa.x, 0,  l_a, A00, A01)                              \
        SOFTMAX_CT(saa, 1, mwa.x, 16, l_a, A10, A11)                              \
        SOFTMAX_CT(saa, 2, mwa.y, 0,  l_a, A20, A21)                              \
        SOFTMAX_CT(saa, 3, mwa.y, 16, l_a, A30, A31)                              \
        SOFTMAX_CT(sab, 0, mwb.x, 0,  l_b, B00, B01)                              \
        SOFTMAX_CT(sab, 1, mwb.x, 16, l_b, B10, B11)                              \
        SOFTMAX_CT(sab, 2, mwb.y, 0,  l_b, B20, B21)                              \
        SOFTMAX_CT(sab, 3, mwb.y, 16, l_b, B30, B31)                              \
        mwa = mwa_nxt; mwb = mwb_nxt;                                             \
        plswap32(A00, A10); plswap32(A01, A11);                                   \
        plswap32(A20, A30); plswap32(A21, A31);                                   \
        plswap16(A00, A10); plswap16(A01, A11);                                   \
        plswap16(A20, A30); plswap16(A21, A31);                                   \
        plswap32(B00, B10); plswap32(B01, B11);                                   \
        plswap32(B20, B30); plswap32(B21, B31);                                   \
        plswap16(B00, B10); plswap16(B01, B11);                                   \
        plswap16(B20, B30); plswap16(B21, B31);                                   \
        const half8 pb0a = __builtin_bit_cast(half8, (int4v){A00, A01, A10, A11});\
        const half8 pb1a = __builtin_bit_cast(half8, (int4v){A20, A21, A30, A31});\
        const half8 pb0b = __builtin_bit_cast(half8, (int4v){B00, B01, B10, B11});\
        const half8 pb1b = __builtin_bit_cast(half8, (int4v){B20, B21, B30, B31});\
        __builtin_amdgcn_s_setprio(1);                                            \
        _Pragma("unroll")                                                         \
        for (int dt = 0; dt < 4; dt++) {                                          \
            const half8 va0 = *(const half8*)&sbase[(RO) + 4096 + (dt*16 + l15)*64 + xs0];\
            const half8 va1 = *(const half8*)&sbase[(RO) + 4096 + (dt*16 + l15)*64 + xs1];\
            oacca[dt] = __builtin_amdgcn_mfma_f32_16x16x32_f16(va0, pb0a, oacca[dt], 0, 0, 0); \
            oacca[dt] = __builtin_amdgcn_mfma_f32_16x16x32_f16(va1, pb1a, oacca[dt], 0, 0, 0); \
            oaccb[dt] = __builtin_amdgcn_mfma_f32_16x16x32_f16(va0, pb0b, oaccb[dt], 0, 0, 0); \
            oaccb[dt] = __builtin_amdgcn_mfma_f32_16x16x32_f16(va1, pb1b, oaccb[dt], 0, 0, 0); \
        }                                                                         \
        __builtin_amdgcn_s_setprio(0);                                            \
        __syncthreads();                                                          \
    }

    for (int kt2 = 0; kt2 < 15; kt2++) {
        ATTN_TILE(0,    8192, 2 * kt2,     1)
        ATTN_TILE(8192, 0,    2 * kt2 + 1, 1)
    }
    ATTN_TILE(0,    8192, 30, 1)
    ATTN_TILE(8192, 0,    31, 0)

#undef ATTN_TILE
#undef SOFTMAX_CT
#undef STAGE

    // l: sum the 4 quad-partials for each qrow (lane bits 4,5)
    l_a += __shfl_xor(l_a, 16, 64);
    l_a += __shfl_xor(l_a, 32, 64);
    l_b += __shfl_xor(l_b, 16, 64);
    l_b += __shfl_xor(l_b, 32, 64);

    // ---- merge the two key-halves via explicit smem re-carve
    __syncthreads();
    float* oex = (float*)smem_raw;                 // 4 waves x 64 lanes x 32 f32 = 32 KB
    float* lex = (float*)(smem_raw + 32768);       // 128 floats
    if (w >= 4) {
        float* dst = &oex[((size_t)(w - 4) * 64 + lane) * 32];
        #pragma unroll
        for (int dt = 0; dt < 4; dt++) {
            *(floatx4*)&dst[dt * 4]      = oacca[dt];
            *(floatx4*)&dst[16 + dt * 4] = oaccb[dt];
        }
        if (quad == 0) {
            lex[(w - 4) * 16 + l15]      = l_a;
            lex[64 + (w - 4) * 16 + l15] = l_b;
        }
    }
    __syncthreads();
    if (w < 4) {
        const float* src = &oex[((size_t)w * 64 + lane) * 32];
        const float lta = l_a + lex[w * 16 + l15];
        const float ltb = l_b + lex[64 + w * 16 + l15];
        const float inva = (lta > 0.f) ? (1.0f / lta) : 0.f;
        const float invb = (ltb > 0.f) ? (1.0f / ltb) : 0.f;
        _Float16* aoba = ao + ((size_t)b * NTOK + q0 + w * 16 + l15) * C_ + h * 64;
        _Float16* aobb = ao + ((size_t)b * NTOK + q0 + 64 + w * 16 + l15) * C_ + h * 64;
        #pragma unroll
        for (int dt = 0; dt < 4; dt++) {
            const floatx4 o2a = *(const floatx4*)&src[dt * 4];
            const floatx4 o2b = *(const floatx4*)&src[16 + dt * 4];
            half4 ra, rb;
            #pragma unroll
            for (int rr = 0; rr < 4; rr++) {
                ra[rr] = (_Float16)((oacca[dt][rr] + o2a[rr]) * inva);
                rb[rr] = (_Float16)((oaccb[dt][rr] + o2b[rr]) * invb);
            }
            *(half4*)&aoba[dt * 16 + quad * 4] = ra;
            *(half4*)&aobb[dt * 16 + quad * 4] = rb;
        }
    }
}

// ---------------------------------------------------------------------------
// Kernel 3: output projection via MFMA (R7-verified: direct-global operands,
// inline W conversion, no main-loop LDS/barriers). UNCHANGED.
// ---------------------------------------------------------------------------
__global__ __launch_bounds__(256) void out_mfma(
    const _Float16* __restrict__ ao, const float* __restrict__ wo,
    const float* __restrict__ bo, float* __restrict__ out)
{
    const int nt  = blockIdx.x;
    const int cot = blockIdx.y;
    const int b   = blockIdx.z;
    const int t    = threadIdx.x;
    const int wid  = t >> 6;
    const int lane = t & 63;
    const int quad = lane >> 4;
    const int l15  = lane & 15;
    const int n0  = nt * 64;
    const int co0 = cot * 64;

    __shared__ float tf[64 * 68];        // [co][tok] epilogue

    floatx4 acc[4];
    #pragma unroll
    for (int i = 0; i < 4; i++) acc[i] = (floatx4)0.f;

    const float* wrow = &wo[(size_t)(co0 + wid * 16 + l15) * C_];
    const _Float16* aob  = ao + ((size_t)b * NTOK + n0) * C_;

    #pragma unroll
    for (int c0 = 0; c0 < C_; c0 += 64) {
        const half8 a0 = ldcvt8(&wrow[c0 + quad * 8]);
        const half8 a1 = ldcvt8(&wrow[c0 + 32 + quad * 8]);
        #pragma unroll
        for (int nt2 = 0; nt2 < 4; nt2++) {
            const half8 b0 = *(const half8*)&aob[(size_t)(nt2 * 16 + l15) * C_ + c0 + quad * 8];
            const half8 b1 = *(const half8*)&aob[(size_t)(nt2 * 16 + l15) * C_ + c0 + 32 + quad * 8];
            acc[nt2] = __builtin_amdgcn_mfma_f32_16x16x32_f16(a0, b0, acc[nt2], 0, 0, 0);
            acc[nt2] = __builtin_amdgcn_mfma_f32_16x16x32_f16(a1, b1, acc[nt2], 0, 0, 0);
        }
    }

    // epilogue: D[co][tok] -> tf, then coalesced fp32 rows + bias
    #pragma unroll
    for (int nt2 = 0; nt2 < 4; nt2++)
        #pragma unroll
        for (int i = 0; i < 4; i++)
            tf[(wid * 16 + quad * 4 + i) * 68 + nt2 * 16 + l15] = acc[nt2][i];
    __syncthreads();

    const int row = t >> 2;              // co local
    const int c4  = (t & 3) * 16;        // tok local
    const float bb = bo[co0 + row];
    float* orow = &out[((size_t)(b * C_ + co0 + row)) * NTOK + n0 + c4];
    #pragma unroll
    for (int u = 0; u < 4; u++) {
        float4 v = *(const float4*)&tf[row * 68 + c4 + u * 4];
        v.x += bb; v.y += bb; v.z += bb; v.w += bb;
        *(float4*)&orow[u * 4] = v;
    }
}

// ---------------------------------------------------------------------------
extern "C" void kernel_launch(void* const* d_in, const int* in_sizes, int n_in,
                              void* d_out, int out_size, void* d_ws, size_t ws_size,
                              hipStream_t stream) {
    const float* x    = (const float*)d_in[0];          // fp32
    const void*  mask = d_in[1];                        // dtype auto-detected
    const float* wq   = (const float*)d_in[2];
    const float* bq   = (const float*)d_in[3];
    const float* wk   = (const float*)d_in[4];
    const float* bk   = (const float*)d_in[5];
    const float* wv   = (const float*)d_in[6];
    const float* bv   = (const float*)d_in[7];
    const float* wo   = (const float*)d_in[8];
    const float* bo   = (const float*)d_in[9];
    float* out = (float*)d_out;                         // fp32

    // workspace layout (f16 units):
    //   q,k,vt,ao: 4 x 2,097,152   | mpacked: 1,048,576 u32 (= 2,097,152)
    const size_t qkv_elems = (size_t)B_ * NHEAD * NTOK * HDIM;  // == B*NTOK*C_
    _Float16* wsh = (_Float16*)d_ws;
    _Float16* qbuf  = wsh;
    _Float16* kbuf  = wsh + qkv_elems;
    _Float16* vtbuf = wsh + 2 * qkv_elems;
    _Float16* aobuf = wsh + 3 * qkv_elems;
    unsigned int* mpacked = (unsigned int*)(wsh + 4 * qkv_elems);

    qkv_pack<<<dim3(QKV_BLOCKS + (B_ * NTOK * 128) / 256), 256, 0, stream>>>(
        x, wq, wk, wv, bq, bk, bv,
        (const unsigned int*)mask, mpacked, qbuf, kbuf, vtbuf);
    attn<<<dim3(NTOK / 128, NHEAD, B_), 512, 0, stream>>>(
        qbuf, kbuf, vtbuf, mpacked, aobuf);
    out_mfma<<<dim3(NTOK / 64, C_ / 64, B_), 256, 0, stream>>>(
        aobuf, wo, bo, out);
}